// Round 1
// baseline (468.656 us; speedup 1.0000x reference)
//
#include <hip/hip_runtime.h>
#include <hip/hip_bf16.h>
#include <stdint.h>

#define EPS 1e-6f

typedef unsigned short ushort_t;
using frag  = __attribute__((ext_vector_type(8))) short;   // 8 bf16
using f32x4 = __attribute__((ext_vector_type(4))) float;   // MFMA acc

__device__ __forceinline__ ushort_t f2bf(float f) {
  uint32_t u = __builtin_bit_cast(uint32_t, f);
  u += 0x7FFFu + ((u >> 16) & 1u);          // round-to-nearest-even
  return (ushort_t)(u >> 16);
}

// ---------------------------------------------------------------------------
// prep: per 64-row block b: normalize rows, G = Vn Vn^T (strict upper),
// T = (0.5 I + triu(G,1))^-1 (stored transposed in lower triangle of gt),
// W_b = T^T Vn. 8 blocks in parallel.
// ---------------------------------------------------------------------------
__global__ __launch_bounds__(1024) void prep_kernel(const float* __restrict__ V,
                                                    float* __restrict__ Vn,
                                                    float* __restrict__ W) {
  __shared__ float vs[64][512];   // 128 KB
  __shared__ float gt[64][64];    // 16 KB: strict upper = G; [k][i] (i<=k) = T[i][k]
  const int b    = blockIdx.x;
  const int tid  = threadIdx.x;
  const int wave = tid >> 6, lane = tid & 63;
  const float* Vb = V + b * 32768;

  // 1. normalize rows (wave per row, 4 rows per wave)
  for (int r = wave; r < 64; r += 16) {
    const float4* row = (const float4*)(Vb + r * 512) + lane * 2;
    float4 a = row[0], c = row[1];
    float s = a.x*a.x + a.y*a.y + a.z*a.z + a.w*a.w
            + c.x*c.x + c.y*c.y + c.z*c.z + c.w*c.w;
    #pragma unroll
    for (int off = 32; off; off >>= 1) s += __shfl_xor(s, off);
    float inv = 1.f / (sqrtf(s) + EPS);
    float4 na = make_float4(a.x*inv, a.y*inv, a.z*inv, a.w*inv);
    float4 nc = make_float4(c.x*inv, c.y*inv, c.z*inv, c.w*inv);
    float4* dl = (float4*)&vs[r][0] + lane * 2;
    dl[0] = na; dl[1] = nc;
    float4* dg = (float4*)(Vn + b * 32768 + r * 512) + lane * 2;
    dg[0] = na; dg[1] = nc;
  }
  __syncthreads();

  // 2. G[i][j] for i<j: one pair per wave (wave-level dot product)
  for (int p = wave; p < 4096; p += 16) {
    int i = p >> 6, j = p & 63;
    if (i >= j) continue;
    const float4* ri = (const float4*)&vs[i][0];
    const float4* rj = (const float4*)&vs[j][0];
    float s = 0.f;
    #pragma unroll
    for (int e = 0; e < 2; ++e) {
      float4 a = ri[lane + 64*e], c = rj[lane + 64*e];
      s += a.x*c.x + a.y*c.y + a.z*c.z + a.w*c.w;
    }
    #pragma unroll
    for (int off = 32; off; off >>= 1) s += __shfl_xor(s, off);
    if (lane == 0) gt[i][j] = s;
  }
  __syncthreads();

  // 3. T = M^-1 by per-lane-column back-substitution, fully unrolled (regs)
  if (wave == 0) {
    const int k = lane;
    float t[64];
    #pragma unroll
    for (int i = 63; i >= 0; --i) {
      float s = (i == k) ? 1.f : 0.f;
      #pragma unroll
      for (int j = i + 1; j < 64; ++j) s -= gt[i][j] * t[j];
      t[i] = 2.f * s;
    }
    #pragma unroll
    for (int i = 0; i < 64; ++i)
      if (i <= k) gt[k][i] = t[i];   // T[i][k] stored at gt[k][i]
  }
  __syncthreads();

  // 4. W[i][c] = sum_{j<=i} T[j][i] * vs[j][c]
  const int i  = tid >> 4;
  const int c0 = tid & 15;
  for (int cc = 0; cc < 32; ++cc) {
    int c = c0 + (cc << 4);
    float acc = 0.f;
    for (int j = 0; j <= i; ++j) acc += gt[i][j] * vs[j][c];
    W[b * 32768 + i * 512 + c] = acc;
  }
}

__global__ void init_q(float* __restrict__ Q) {
  int m = blockIdx.x, t = threadIdx.x;
  Q[m * 512 + t] = (m == t) ? 1.f : 0.f;
}

// A[m][n] = sum_k Q[m][k] * Wb[n][k]   (M=512, N=64, K=512)
__global__ __launch_bounds__(256) void gemmA_kernel(const float* __restrict__ Q,
                                                    const float* __restrict__ Wb,
                                                    float* __restrict__ A) {
  int n = blockIdx.x * 16 + (threadIdx.x & 15);
  int m = blockIdx.y * 16 + (threadIdx.x >> 4);
  const float4* q = (const float4*)(Q + m * 512);
  const float4* w = (const float4*)(Wb + n * 512);
  float acc = 0.f;
  #pragma unroll 4
  for (int e = 0; e < 128; ++e) {
    float4 a = q[e], c = w[e];
    acc += a.x*c.x + a.y*c.y + a.z*c.z + a.w*c.w;
  }
  A[m * 64 + n] = acc;
}

// Q[m][k] -= sum_n A[m][n] * Vb[n][k]  (rank-64 update)
__global__ __launch_bounds__(256) void rank_update_kernel(float* __restrict__ Q,
                                                          const float* __restrict__ A,
                                                          const float* __restrict__ Vb) {
  int k = blockIdx.x * 256 + threadIdx.x;
  int m = blockIdx.y;
  const float* a = A + m * 64;
  float acc = 0.f;
  #pragma unroll
  for (int n = 0; n < 64; ++n) acc += a[n] * Vb[n * 512 + k];
  Q[m * 512 + k] -= acc;
}

__global__ __launch_bounds__(256) void cast_kernel(const float* __restrict__ Q,
                                                   ushort_t* __restrict__ Qb) {
  int idx = (blockIdx.x * 256 + threadIdx.x) * 4;
  float4 f = *(const float4*)(Q + idx);
  ushort4 o;
  o.x = f2bf(f.x); o.y = f2bf(f.y); o.z = f2bf(f.z); o.w = f2bf(f.w);
  *(ushort4*)(Qb + idx) = o;
}

// ---------------------------------------------------------------------------
// out[m][n] = sum_k x[m][k] * Q[n][k]   M=131072 N=512 K=512
// BM=128 BN=512(full, x read once) BK=64, 8 waves (2x4), 16x16x32 bf16 MFMA
// ---------------------------------------------------------------------------
__global__ __launch_bounds__(512, 2) void final_gemm(const float* __restrict__ X,
                                                     const ushort_t* __restrict__ Qb,
                                                     float* __restrict__ out) {
  __shared__ __align__(16) ushort_t As[128 * 64];   // 16 KB, XOR-swizzled
  __shared__ __align__(16) ushort_t Bs[512 * 64];   // 64 KB, XOR-swizzled
  const int tid = threadIdx.x;
  const int wid = tid >> 6, lane = tid & 63;
  const int wm = wid >> 2, wn = wid & 3;            // 2 x 4 wave grid
  const int m0 = blockIdx.x * 128;

  f32x4 acc[4][8];
  #pragma unroll
  for (int i = 0; i < 4; ++i)
    #pragma unroll
    for (int j = 0; j < 8; ++j) acc[i][j] = (f32x4){0.f, 0.f, 0.f, 0.f};

  for (int kt = 0; kt < 8; ++kt) {
    // stage A: f32 -> bf16, swizzled ds_write_b128
    #pragma unroll
    for (int h = 0; h < 2; ++h) {
      int d = tid + h * 512;                 // data chunk: 8 bf16
      int row = d >> 3, ks = d & 7;
      const float4* src = (const float4*)(X + (m0 + row) * 512 + kt * 64 + ks * 8);
      float4 f0 = src[0], f1 = src[1];
      frag v;
      v[0] = (short)f2bf(f0.x); v[1] = (short)f2bf(f0.y);
      v[2] = (short)f2bf(f0.z); v[3] = (short)f2bf(f0.w);
      v[4] = (short)f2bf(f1.x); v[5] = (short)f2bf(f1.y);
      v[6] = (short)f2bf(f1.z); v[7] = (short)f2bf(f1.w);
      int o = row * 128 + ((ks ^ (row & 7)) << 4);
      *(frag*)((char*)As + o) = v;
    }
    // stage B: global_load_lds, linear LDS dest + inverse-swizzled source
    #pragma unroll
    for (int it = 0; it < 8; ++it) {
      int s = it * 8 + wid;                  // 1 KB segment
      int j = s * 8 + (lane >> 3);
      int slot = lane & 7;
      const ushort_t* gsrc = Qb + j * 512 + kt * 64 + ((slot ^ (j & 7)) << 3);
      __builtin_amdgcn_global_load_lds(
          (const __attribute__((address_space(1))) uint32_t*)gsrc,
          (__attribute__((address_space(3))) uint32_t*)((char*)Bs + s * 1024),
          16, 0, 0);
    }
    __syncthreads();

    #pragma unroll
    for (int ks2 = 0; ks2 < 2; ++ks2) {
      frag a[4], bf[8];
      int kb = ks2 * 64 + ((lane >> 4) << 4);
      #pragma unroll
      for (int mf = 0; mf < 4; ++mf) {
        int r = wm * 64 + mf * 16 + (lane & 15);
        a[mf] = *(const frag*)((const char*)As + r * 128 + (kb ^ ((r & 7) << 4)));
      }
      #pragma unroll
      for (int nf = 0; nf < 8; ++nf) {
        int r = wn * 128 + nf * 16 + (lane & 15);
        bf[nf] = *(const frag*)((const char*)Bs + r * 128 + (kb ^ ((r & 7) << 4)));
      }
      #pragma unroll
      for (int mf = 0; mf < 4; ++mf)
        #pragma unroll
        for (int nf = 0; nf < 8; ++nf)
          acc[mf][nf] = __builtin_amdgcn_mfma_f32_16x16x32_bf16(a[mf], bf[nf], acc[mf][nf], 0, 0, 0);
    }
    __syncthreads();
  }

  // epilogue: C/D map col=lane&15, row=(lane>>4)*4+reg
  #pragma unroll
  for (int mf = 0; mf < 4; ++mf) {
    int rbase = m0 + wm * 64 + mf * 16 + ((lane >> 4) << 2);
    #pragma unroll
    for (int nf = 0; nf < 8; ++nf) {
      int col = wn * 128 + nf * 16 + (lane & 15);
      #pragma unroll
      for (int r = 0; r < 4; ++r)
        out[(rbase + r) * 512 + col] = acc[mf][nf][r];
    }
  }
}

extern "C" void kernel_launch(void* const* d_in, const int* in_sizes, int n_in,
                              void* d_out, int out_size, void* d_ws, size_t ws_size,
                              hipStream_t stream) {
  const float* x = (const float*)d_in[0];
  const float* V = (const float*)d_in[1];   // hd_vecs[0]: 512 x 512
  float* out = (float*)d_out;
  float* ws  = (float*)d_ws;

  float*    Vn = ws;                         // 262144 f32
  float*    W  = ws + 262144;                // 262144 f32
  float*    Q  = ws + 524288;                // 262144 f32
  float*    A  = ws + 786432;                // 32768  f32
  ushort_t* Qb = (ushort_t*)(ws + 819200);   // 262144 bf16

  prep_kernel<<<8, 1024, 0, stream>>>(V, Vn, W);
  init_q<<<512, 512, 0, stream>>>(Q);
  for (int b = 0; b < 8; ++b) {
    gemmA_kernel<<<dim3(4, 32), 256, 0, stream>>>(Q, W + b * 32768, A);
    rank_update_kernel<<<dim3(2, 512), 256, 0, stream>>>(Q, A, Vn + b * 32768);
  }
  cast_kernel<<<256, 256, 0, stream>>>(Q, Qb);
  final_gemm<<<1024, 512, 0, stream>>>(x, Qb, out);
}

// Round 2
// 422.814 us; speedup vs baseline: 1.1084x; 1.1084x over previous
//
#include <hip/hip_runtime.h>
#include <hip/hip_bf16.h>
#include <stdint.h>

#define EPS 1e-6f

typedef unsigned short ushort_t;
using frag  = __attribute__((ext_vector_type(8))) short;   // 8 bf16
using f32x4 = __attribute__((ext_vector_type(4))) float;   // MFMA acc
using fv4   = __attribute__((ext_vector_type(4))) float;

__device__ __forceinline__ ushort_t f2bf(float f) {
  uint32_t u = __builtin_bit_cast(uint32_t, f);
  u += 0x7FFFu + ((u >> 16) & 1u);          // round-to-nearest-even
  return (ushort_t)(u >> 16);
}

// ---------------------------------------------------------------------------
// P1: normalize rows. One wave per row (512 rows).
// ---------------------------------------------------------------------------
__global__ __launch_bounds__(256) void normalize_kernel(const float* __restrict__ V,
                                                        float* __restrict__ Vn) {
  const int gw   = blockIdx.x * 4 + (threadIdx.x >> 6);   // row 0..511
  const int lane = threadIdx.x & 63;
  const float4* src = (const float4*)(V + gw * 512) + lane * 2;
  float4 a = src[0], c = src[1];
  float s = a.x*a.x + a.y*a.y + a.z*a.z + a.w*a.w
          + c.x*c.x + c.y*c.y + c.z*c.z + c.w*c.w;
  #pragma unroll
  for (int off = 32; off; off >>= 1) s += __shfl_xor(s, off);
  float inv = 1.f / (sqrtf(s) + EPS);
  float4 na = make_float4(a.x*inv, a.y*inv, a.z*inv, a.w*inv);
  float4 nc = make_float4(c.x*inv, c.y*inv, c.z*inv, c.w*inv);
  float4* dst = (float4*)(Vn + gw * 512) + lane * 2;
  dst[0] = na; dst[1] = nc;
}

// ---------------------------------------------------------------------------
// P2: G[b][i][j] = <Vn_b[i], Vn_b[j]> for j>i. One wave per (b,i).
// ---------------------------------------------------------------------------
__global__ __launch_bounds__(256) void gram_kernel(const float* __restrict__ Vn,
                                                   float* __restrict__ G) {
  const int gw   = blockIdx.x * 4 + (threadIdx.x >> 6);   // 0..511
  const int b    = gw >> 7, i = gw & 127;
  const int lane = threadIdx.x & 63;
  const float4* ri = (const float4*)(Vn + (b * 128 + i) * 512) + lane * 2;
  float4 a0 = ri[0], a1 = ri[1];
  #pragma unroll 2
  for (int j = i + 1; j < 128; ++j) {
    const float4* rj = (const float4*)(Vn + (b * 128 + j) * 512) + lane * 2;
    float4 c0 = rj[0], c1 = rj[1];
    float s = a0.x*c0.x + a0.y*c0.y + a0.z*c0.z + a0.w*c0.w
            + a1.x*c1.x + a1.y*c1.y + a1.z*c1.z + a1.w*c1.w;
    #pragma unroll
    for (int off = 32; off; off >>= 1) s += __shfl_xor(s, off);
    if (lane == 0) G[(b * 128 + i) * 128 + j] = s;
  }
}

// ---------------------------------------------------------------------------
// P3: T = (0.5 I + triu(G,1))^-1 for a 128x128 block, blocked 2x2:
//   M = [[A,B],[0,D]],  T = [[Ai, -Ai*B*Di],[0, Di]]
// Ai, Di via per-lane-column back-substitution (64-deep, fully unrolled).
// Writes Tt (= T transposed) over the G buffer. Grid = 4 blocks (one per b).
// ---------------------------------------------------------------------------
__global__ __launch_bounds__(256) void trinv_kernel(float* __restrict__ GT) {
  __shared__ float Gs[128][132];    // 67.6 KB (132: 16B-aligned rows, banks spread)
  __shared__ float Ai[64][68];      // 17 KB each
  __shared__ float Di[64][68];
  __shared__ float C1[64][68];
  const int b = blockIdx.x, tid = threadIdx.x;
  float* Gg = GT + b * 16384;

  // coop load G (full 128x128; garbage below diag never read)
  {
    const int r = tid >> 1, h = tid & 1;
    const float4* src = (const float4*)(Gg + r * 128 + h * 64);
    float4* dst = (float4*)(&Gs[r][h * 64]);
    #pragma unroll
    for (int e = 0; e < 16; ++e) dst[e] = src[e];
  }
  __syncthreads();

  const int wave = tid >> 6, lane = tid & 63;
  if (wave < 2) {                   // wave0: A-quadrant inverse, wave1: D-quadrant
    const int o = wave * 64;
    float t[64];
    #pragma unroll
    for (int i = 63; i >= 0; --i) {
      float s = (i == lane) ? 1.f : 0.f;
      #pragma unroll
      for (int j = i + 1; j < 64; ++j) s -= Gs[o + i][o + j] * t[j];
      t[i] = 2.f * s;
    }
    float (*OUT)[68] = wave ? Di : Ai;
    #pragma unroll
    for (int i = 0; i < 64; ++i) OUT[i][lane] = t[i];
  }
  __syncthreads();

  const int i0 = (tid >> 4) << 2;   // 4x4 register tiles
  const int j0 = (tid & 15) << 2;

  // C1 = B * Di,  B[i][l] = Gs[i][64+l]
  {
    fv4 acc[4] = {};
    for (int l = 0; l < 64; l += 4) {
      fv4 g[4], d[4];
      #pragma unroll
      for (int r = 0; r < 4; ++r) g[r] = *(const fv4*)(&Gs[i0 + r][64 + l]);
      #pragma unroll
      for (int r = 0; r < 4; ++r) d[r] = *(const fv4*)(&Di[l + r][j0]);
      #pragma unroll
      for (int r = 0; r < 4; ++r)
        #pragma unroll
        for (int l2 = 0; l2 < 4; ++l2) {
          #pragma unroll
          for (int q = 0; q < 4; ++q)
            acc[r][q] = fmaf(g[r][l2], d[l2][q], acc[r][q]);
        }
    }
    #pragma unroll
    for (int r = 0; r < 4; ++r) *(fv4*)(&C1[i0 + r][j0]) = acc[r];
  }
  __syncthreads();

  // corner = -Ai * C1 ; write transposed directly: Tt[64+j][i] = corner[i][j]
  {
    fv4 acc[4] = {};
    for (int l = 0; l < 64; l += 4) {
      fv4 g[4], d[4];
      #pragma unroll
      for (int r = 0; r < 4; ++r) g[r] = *(const fv4*)(&Ai[i0 + r][l]);
      #pragma unroll
      for (int r = 0; r < 4; ++r) d[r] = *(const fv4*)(&C1[l + r][j0]);
      #pragma unroll
      for (int r = 0; r < 4; ++r)
        #pragma unroll
        for (int l2 = 0; l2 < 4; ++l2) {
          #pragma unroll
          for (int q = 0; q < 4; ++q)
            acc[r][q] = fmaf(g[r][l2], d[l2][q], acc[r][q]);
        }
    }
    #pragma unroll
    for (int r = 0; r < 4; ++r)
      #pragma unroll
      for (int q = 0; q < 4; ++q)
        Gg[(64 + j0 + q) * 128 + (i0 + r)] = -acc[r][q];
  }

  // remaining quadrants of Tt: row j, half h
  {
    const int j = tid >> 1, h = tid & 1;
    if (j < 64) {
      if (h == 0) { for (int i = 0; i < 64; ++i) Gg[j * 128 + i] = Ai[i][j]; }
      else        { for (int i = 0; i < 64; ++i) Gg[j * 128 + 64 + i] = 0.f; }
    } else if (h == 1) {
      for (int i = 0; i < 64; ++i) Gg[j * 128 + 64 + i] = Di[i][j - 64];
    }
  }
}

// ---------------------------------------------------------------------------
// P4: W_b = Tt_b * Vn_b   (128x128)*(128x512), dense. Grid 32 = 4b x 8 itiles.
// ---------------------------------------------------------------------------
__global__ __launch_bounds__(256) void wbuild_kernel(const float* __restrict__ GT,
                                                     const float* __restrict__ Vn,
                                                     float* __restrict__ W) {
  const int b = blockIdx.x >> 3, itile = blockIdx.x & 7;
  const int tid = threadIdx.x;
  const int i  = itile * 16 + (tid >> 4);
  const int c0 = (tid & 15) * 32;
  const float* trow = GT + b * 16384 + i * 128;
  const float* vb   = Vn + b * 65536 + c0;
  fv4 acc[8] = {};
  #pragma unroll 2
  for (int j = 0; j < 128; ++j) {
    float t = trow[j];
    const fv4* v = (const fv4*)(vb + j * 512);
    #pragma unroll
    for (int e = 0; e < 8; ++e) {
      #pragma unroll
      for (int q = 0; q < 4; ++q) acc[e][q] = fmaf(t, v[e][q], acc[e][q]);
    }
  }
  float* wrow = W + b * 65536 + i * 512 + c0;
  #pragma unroll
  for (int e = 0; e < 8; ++e) *(fv4*)(wrow + e * 4) = acc[e];
}

// ---------------------------------------------------------------------------
// Chain. Iter 0 fused (Q = I  =>  A0 = W0^T):
//   Q[m][k] = delta(m,k) - sum_n W0[n][m] * Vn0[n][k]
// ---------------------------------------------------------------------------
__global__ __launch_bounds__(256) void update0_kernel(const float* __restrict__ W,
                                                      const float* __restrict__ Vn,
                                                      float* __restrict__ Q) {
  const int k = blockIdx.x * 256 + threadIdx.x;
  const int m = blockIdx.y;
  float acc = 0.f;
  #pragma unroll 4
  for (int n = 0; n < 128; ++n)
    acc = fmaf(W[n * 512 + m], Vn[n * 512 + k], acc);
  Q[m * 512 + k] = ((m == k) ? 1.f : 0.f) - acc;
}

// A[m][n] = sum_k Q[m][k] * Wb[n][k]   (512 x 128, K=512)
__global__ __launch_bounds__(256) void gemmA_kernel(const float* __restrict__ Q,
                                                    const float* __restrict__ Wb,
                                                    float* __restrict__ A) {
  const int n = blockIdx.x * 16 + (threadIdx.x & 15);
  const int m = blockIdx.y * 16 + (threadIdx.x >> 4);
  const float4* q = (const float4*)(Q + m * 512);
  const float4* w = (const float4*)(Wb + n * 512);
  float acc = 0.f;
  #pragma unroll 4
  for (int e = 0; e < 128; ++e) {
    float4 a = q[e], c = w[e];
    acc += a.x*c.x + a.y*c.y + a.z*c.z + a.w*c.w;
  }
  A[m * 128 + n] = acc;
}

// Q[m][k] -= sum_n A[m][n] * Vn_b[n][k]; last iter writes bf16 Q only.
template<bool LAST>
__global__ __launch_bounds__(256) void update_kernel(float* __restrict__ Q,
                                                     const float* __restrict__ A,
                                                     const float* __restrict__ Vn,
                                                     ushort_t* __restrict__ Qb) {
  const int k = blockIdx.x * 256 + threadIdx.x;
  const int m = blockIdx.y;
  const float* a = A + m * 128;
  float acc = 0.f;
  #pragma unroll 4
  for (int n = 0; n < 128; ++n)
    acc = fmaf(a[n], Vn[n * 512 + k], acc);
  float r = Q[m * 512 + k] - acc;
  if (LAST) Qb[m * 512 + k] = f2bf(r);
  else      Q[m * 512 + k] = r;
}

// ---------------------------------------------------------------------------
// out[m][n] = sum_k x[m][k] * Q[n][k]   M=131072 N=512 K=512
// BM=128 BN=512(full, x read once) BK=64, 8 waves (2x4), 16x16x32 bf16 MFMA
// ---------------------------------------------------------------------------
__global__ __launch_bounds__(512, 2) void final_gemm(const float* __restrict__ X,
                                                     const ushort_t* __restrict__ Qb,
                                                     float* __restrict__ out) {
  __shared__ __align__(16) ushort_t As[128 * 64];   // 16 KB, XOR-swizzled
  __shared__ __align__(16) ushort_t Bs[512 * 64];   // 64 KB, XOR-swizzled
  const int tid = threadIdx.x;
  const int wid = tid >> 6, lane = tid & 63;
  const int wm = wid >> 2, wn = wid & 3;            // 2 x 4 wave grid
  const int m0 = blockIdx.x * 128;

  f32x4 acc[4][8];
  #pragma unroll
  for (int i = 0; i < 4; ++i)
    #pragma unroll
    for (int j = 0; j < 8; ++j) acc[i][j] = (f32x4){0.f, 0.f, 0.f, 0.f};

  for (int kt = 0; kt < 8; ++kt) {
    // stage A: f32 -> bf16, swizzled ds_write_b128
    #pragma unroll
    for (int h = 0; h < 2; ++h) {
      int d = tid + h * 512;                 // data chunk: 8 bf16
      int row = d >> 3, ks = d & 7;
      const float4* src = (const float4*)(X + (m0 + row) * 512 + kt * 64 + ks * 8);
      float4 f0 = src[0], f1 = src[1];
      frag v;
      v[0] = (short)f2bf(f0.x); v[1] = (short)f2bf(f0.y);
      v[2] = (short)f2bf(f0.z); v[3] = (short)f2bf(f0.w);
      v[4] = (short)f2bf(f1.x); v[5] = (short)f2bf(f1.y);
      v[6] = (short)f2bf(f1.z); v[7] = (short)f2bf(f1.w);
      int o = row * 128 + ((ks ^ (row & 7)) << 4);
      *(frag*)((char*)As + o) = v;
    }
    // stage B: global_load_lds, linear LDS dest + inverse-swizzled source
    #pragma unroll
    for (int it = 0; it < 8; ++it) {
      int s = it * 8 + wid;                  // 1 KB segment
      int j = s * 8 + (lane >> 3);
      int slot = lane & 7;
      const ushort_t* gsrc = Qb + j * 512 + kt * 64 + ((slot ^ (j & 7)) << 3);
      __builtin_amdgcn_global_load_lds(
          (const __attribute__((address_space(1))) uint32_t*)gsrc,
          (__attribute__((address_space(3))) uint32_t*)((char*)Bs + s * 1024),
          16, 0, 0);
    }
    __syncthreads();

    #pragma unroll
    for (int ks2 = 0; ks2 < 2; ++ks2) {
      frag a[4], bf[8];
      int kb = ks2 * 64 + ((lane >> 4) << 4);
      #pragma unroll
      for (int mf = 0; mf < 4; ++mf) {
        int r = wm * 64 + mf * 16 + (lane & 15);
        a[mf] = *(const frag*)((const char*)As + r * 128 + (kb ^ ((r & 7) << 4)));
      }
      #pragma unroll
      for (int nf = 0; nf < 8; ++nf) {
        int r = wn * 128 + nf * 16 + (lane & 15);
        bf[nf] = *(const frag*)((const char*)Bs + r * 128 + (kb ^ ((r & 7) << 4)));
      }
      #pragma unroll
      for (int mf = 0; mf < 4; ++mf)
        #pragma unroll
        for (int nf = 0; nf < 8; ++nf)
          acc[mf][nf] = __builtin_amdgcn_mfma_f32_16x16x32_bf16(a[mf], bf[nf], acc[mf][nf], 0, 0, 0);
    }
    __syncthreads();
  }

  // epilogue: C/D map col=lane&15, row=(lane>>4)*4+reg
  #pragma unroll
  for (int mf = 0; mf < 4; ++mf) {
    int rbase = m0 + wm * 64 + mf * 16 + ((lane >> 4) << 2);
    #pragma unroll
    for (int nf = 0; nf < 8; ++nf) {
      int col = wn * 128 + nf * 16 + (lane & 15);
      #pragma unroll
      for (int r = 0; r < 4; ++r)
        out[(rbase + r) * 512 + col] = acc[mf][nf][r];
    }
  }
}

extern "C" void kernel_launch(void* const* d_in, const int* in_sizes, int n_in,
                              void* d_out, int out_size, void* d_ws, size_t ws_size,
                              hipStream_t stream) {
  const float* x = (const float*)d_in[0];
  const float* V = (const float*)d_in[1];   // hd_vecs[0]: 512 x 512
  float* out = (float*)d_out;
  float* ws  = (float*)d_ws;

  float* Vn = ws;                  // 262144 f32
  float* GT = ws + 262144;         // 65536  f32 (G, then Tt in-place)
  float* W  = ws + 327680;         // 262144 f32
  float* Q  = ws + 589824;         // 262144 f32
  float* A  = ws + 851968;         // 65536  f32
  ushort_t* Qb = (ushort_t*)W;     // aliases W[0..1] (dead after last gemmA)

  normalize_kernel<<<128, 256, 0, stream>>>(V, Vn);
  gram_kernel<<<128, 256, 0, stream>>>(Vn, GT);
  trinv_kernel<<<4, 256, 0, stream>>>(GT);
  wbuild_kernel<<<32, 256, 0, stream>>>(GT, Vn, W);
  update0_kernel<<<dim3(2, 512), 256, 0, stream>>>(W, Vn, Q);
  for (int b = 1; b < 4; ++b) {
    gemmA_kernel<<<dim3(8, 32), 256, 0, stream>>>(Q, W + b * 65536, A);
    if (b < 3)
      update_kernel<false><<<dim3(2, 512), 256, 0, stream>>>(Q, A, Vn + b * 65536, nullptr);
    else
      update_kernel<true><<<dim3(2, 512), 256, 0, stream>>>(Q, A, Vn + b * 65536, Qb);
  }
  final_gemm<<<1024, 512, 0, stream>>>(x, Qb, out);
}

// Round 3
// 337.802 us; speedup vs baseline: 1.3874x; 1.2517x over previous
//
#include <hip/hip_runtime.h>
#include <hip/hip_bf16.h>
#include <stdint.h>

#define EPS 1e-6f

typedef unsigned short ushort_t;
using frag  = __attribute__((ext_vector_type(8))) short;   // 8 bf16
using f32x4 = __attribute__((ext_vector_type(4))) float;   // MFMA acc
using fv4   = __attribute__((ext_vector_type(4))) float;

__device__ __forceinline__ ushort_t f2bf(float f) {
  uint32_t u = __builtin_bit_cast(uint32_t, f);
  u += 0x7FFFu + ((u >> 16) & 1u);          // round-to-nearest-even
  return (ushort_t)(u >> 16);
}

// ---------------------------------------------------------------------------
// P1: normalize rows. One wave per row (512 rows).
// ---------------------------------------------------------------------------
__global__ __launch_bounds__(256) void normalize_kernel(const float* __restrict__ V,
                                                        float* __restrict__ Vn) {
  const int gw   = blockIdx.x * 4 + (threadIdx.x >> 6);   // row 0..511
  const int lane = threadIdx.x & 63;
  const float4* src = (const float4*)(V + gw * 512) + lane * 2;
  float4 a = src[0], c = src[1];
  float s = a.x*a.x + a.y*a.y + a.z*a.z + a.w*a.w
          + c.x*c.x + c.y*c.y + c.z*c.z + c.w*c.w;
  #pragma unroll
  for (int off = 32; off; off >>= 1) s += __shfl_xor(s, off);
  float inv = 1.f / (sqrtf(s) + EPS);
  float4 na = make_float4(a.x*inv, a.y*inv, a.z*inv, a.w*inv);
  float4 nc = make_float4(c.x*inv, c.y*inv, c.z*inv, c.w*inv);
  float4* dst = (float4*)(Vn + gw * 512) + lane * 2;
  dst[0] = na; dst[1] = nc;
}

// ---------------------------------------------------------------------------
// P2: G[b][i][j] = <Vn_b[i], Vn_b[j]> for j>i. One wave per (b,i).
// ---------------------------------------------------------------------------
__global__ __launch_bounds__(256) void gram_kernel(const float* __restrict__ Vn,
                                                   float* __restrict__ G) {
  const int gw   = blockIdx.x * 4 + (threadIdx.x >> 6);   // 0..511
  const int b    = gw >> 7, i = gw & 127;
  const int lane = threadIdx.x & 63;
  const float4* ri = (const float4*)(Vn + (b * 128 + i) * 512) + lane * 2;
  float4 a0 = ri[0], a1 = ri[1];
  #pragma unroll 2
  for (int j = i + 1; j < 128; ++j) {
    const float4* rj = (const float4*)(Vn + (b * 128 + j) * 512) + lane * 2;
    float4 c0 = rj[0], c1 = rj[1];
    float s = a0.x*c0.x + a0.y*c0.y + a0.z*c0.z + a0.w*c0.w
            + a1.x*c1.x + a1.y*c1.y + a1.z*c1.z + a1.w*c1.w;
    #pragma unroll
    for (int off = 32; off; off >>= 1) s += __shfl_xor(s, off);
    if (lane == 0) G[(b * 128 + i) * 128 + j] = s;
  }
}

// ---------------------------------------------------------------------------
// P3: Tt = transpose((0.5 I + triu(G,1))^-1) per 128-block, in place over G.
// ---------------------------------------------------------------------------
__global__ __launch_bounds__(256) void trinv_kernel(float* __restrict__ GT) {
  __shared__ float Gs[128][132];
  __shared__ float Ai[64][68];
  __shared__ float Di[64][68];
  __shared__ float C1[64][68];
  const int b = blockIdx.x, tid = threadIdx.x;
  float* Gg = GT + b * 16384;

  {
    const int r = tid >> 1, h = tid & 1;
    const float4* src = (const float4*)(Gg + r * 128 + h * 64);
    float4* dst = (float4*)(&Gs[r][h * 64]);
    #pragma unroll
    for (int e = 0; e < 16; ++e) dst[e] = src[e];
  }
  __syncthreads();

  const int wave = tid >> 6, lane = tid & 63;
  if (wave < 2) {
    const int o = wave * 64;
    float t[64];
    #pragma unroll
    for (int i = 63; i >= 0; --i) {
      float s = (i == lane) ? 1.f : 0.f;
      #pragma unroll
      for (int j = i + 1; j < 64; ++j) s -= Gs[o + i][o + j] * t[j];
      t[i] = 2.f * s;
    }
    float (*OUT)[68] = wave ? Di : Ai;
    #pragma unroll
    for (int i = 0; i < 64; ++i) OUT[i][lane] = t[i];
  }
  __syncthreads();

  const int i0 = (tid >> 4) << 2;
  const int j0 = (tid & 15) << 2;

  {  // C1 = B * Di
    fv4 acc[4] = {};
    for (int l = 0; l < 64; l += 4) {
      fv4 g[4], d[4];
      #pragma unroll
      for (int r = 0; r < 4; ++r) g[r] = *(const fv4*)(&Gs[i0 + r][64 + l]);
      #pragma unroll
      for (int r = 0; r < 4; ++r) d[r] = *(const fv4*)(&Di[l + r][j0]);
      #pragma unroll
      for (int r = 0; r < 4; ++r)
        #pragma unroll
        for (int l2 = 0; l2 < 4; ++l2)
          #pragma unroll
          for (int q = 0; q < 4; ++q)
            acc[r][q] = fmaf(g[r][l2], d[l2][q], acc[r][q]);
    }
    #pragma unroll
    for (int r = 0; r < 4; ++r) *(fv4*)(&C1[i0 + r][j0]) = acc[r];
  }
  __syncthreads();

  {  // corner = -Ai*C1, write transposed
    fv4 acc[4] = {};
    for (int l = 0; l < 64; l += 4) {
      fv4 g[4], d[4];
      #pragma unroll
      for (int r = 0; r < 4; ++r) g[r] = *(const fv4*)(&Ai[i0 + r][l]);
      #pragma unroll
      for (int r = 0; r < 4; ++r) d[r] = *(const fv4*)(&C1[l + r][j0]);
      #pragma unroll
      for (int r = 0; r < 4; ++r)
        #pragma unroll
        for (int l2 = 0; l2 < 4; ++l2)
          #pragma unroll
          for (int q = 0; q < 4; ++q)
            acc[r][q] = fmaf(g[r][l2], d[l2][q], acc[r][q]);
    }
    #pragma unroll
    for (int r = 0; r < 4; ++r)
      #pragma unroll
      for (int q = 0; q < 4; ++q)
        Gg[(64 + j0 + q) * 128 + (i0 + r)] = -acc[r][q];
  }

  {
    const int j = tid >> 1, h = tid & 1;
    if (j < 64) {
      if (h == 0) { for (int i = 0; i < 64; ++i) Gg[j * 128 + i] = Ai[i][j]; }
      else        { for (int i = 0; i < 64; ++i) Gg[j * 128 + 64 + i] = 0.f; }
    } else if (h == 1) {
      for (int i = 0; i < 64; ++i) Gg[j * 128 + 64 + i] = Di[i][j - 64];
    }
  }
}

// ---------------------------------------------------------------------------
// Fused chain: block owns 4 Q-rows; loops b=0..3 with
//   P = Qt·Vn_b^T ; A = P·T_b (= P·Tt^T) ; Qt -= A·Vn_b
// Epilogue writes Qf in MFMA-B fragment order (bf16).
// Qf entry: Qf[((ks*32+nt)*64+l)*8 + j] = Q[nt*16+(l&15)][ks*32+(l>>4)*8+j]
// ---------------------------------------------------------------------------
__global__ __launch_bounds__(256) void chain_kernel(const float* __restrict__ Vn,
                                                    const float* __restrict__ Tt,
                                                    ushort_t* __restrict__ Qf) {
  __shared__ float Qt[4][512];          // 8 KB
  __shared__ float Vc[32768];           // 128 KB: 64 rows x 2048 B, XOR-swizzled
  __shared__ float Pp[4][4][64];        // 4 KB wave partials
  __shared__ float Ps[4][128];          // 2 KB
  __shared__ float Asm[4][128];         // 2 KB
  const int t = threadIdx.x, w = t >> 6, lane = t & 63;
  const int m0 = blockIdx.x * 4;
  char* VcB = (char*)Vc;

  for (int idx = t; idx < 2048; idx += 256) {
    int i = idx >> 9, k = idx & 511;
    Qt[i][k] = (m0 + i == k) ? 1.f : 0.f;
  }

  for (int b = 0; b < 4; ++b) {
    // ---- P[4][128]
    if (b == 0) {
      __syncthreads();
      if (t < 128) {
        #pragma unroll
        for (int i = 0; i < 4; ++i) Ps[i][t] = Vn[t * 512 + m0 + i];
      }
      __syncthreads();
    } else {
      for (int ch = 0; ch < 2; ++ch) {
        __syncthreads();
        // stage 64 Vn rows into Vc (swizzled)
        #pragma unroll 4
        for (int q = 0; q < 32; ++q) {
          int s = q * 256 + t;
          int r = s >> 7, c4 = s & 127;
          float4 v = *(const float4*)(Vn + (b * 128 + ch * 64 + r) * 512 + c4 * 4);
          *(float4*)(VcB + r * 2048 + ((c4 * 16) ^ ((r & 7) << 4))) = v;
        }
        __syncthreads();
        // wave w: k-quarter [w*128, w*128+128); lane = n
        float pa[4] = {0.f, 0.f, 0.f, 0.f};
        #pragma unroll 4
        for (int k4 = 0; k4 < 32; ++k4) {
          int kk = w * 128 + k4 * 4;
          float4 vv = *(const float4*)(VcB + lane * 2048 + ((kk * 4) ^ ((lane & 7) << 4)));
          #pragma unroll
          for (int i = 0; i < 4; ++i) {
            float4 qq = *(const float4*)(&Qt[i][kk]);
            pa[i] += qq.x*vv.x + qq.y*vv.y + qq.z*vv.z + qq.w*vv.w;
          }
        }
        #pragma unroll
        for (int i = 0; i < 4; ++i) Pp[w][i][lane] = pa[i];
        __syncthreads();
        if (w < 2) {
          #pragma unroll
          for (int i2 = 0; i2 < 2; ++i2) {
            int i = w * 2 + i2;
            Ps[i][ch * 64 + lane] = Pp[0][i][lane] + Pp[1][i][lane]
                                  + Pp[2][i][lane] + Pp[3][i][lane];
          }
        }
      }
      __syncthreads();
    }
    // ---- A[i][n] = sum_j P[i][j] * Tt_b[n][j]; thread: n=t>>1, j-half=t&1
    {
      const float* trow = Tt + b * 16384 + (t >> 1) * 128 + (t & 1) * 64;
      float aa[4] = {0.f, 0.f, 0.f, 0.f};
      #pragma unroll 4
      for (int j4 = 0; j4 < 16; ++j4) {
        float4 tv = *(const float4*)(trow + j4 * 4);
        int j = (t & 1) * 64 + j4 * 4;
        #pragma unroll
        for (int i = 0; i < 4; ++i) {
          float4 pv = *(const float4*)(&Ps[i][j]);
          aa[i] += pv.x*tv.x + pv.y*tv.y + pv.z*tv.z + pv.w*tv.w;
        }
      }
      #pragma unroll
      for (int i = 0; i < 4; ++i) {
        float o = __shfl_xor(aa[i], 1);
        if ((t & 1) == 0) Asm[i][t >> 1] = aa[i] + o;
      }
    }
    // ---- update: Qt[i][c] -= sum_n A[i][n] Vn_b[n][c]; thread owns cols 2t,2t+1
    for (int ch = 0; ch < 2; ++ch) {
      __syncthreads();
      #pragma unroll 4
      for (int q = 0; q < 32; ++q) {
        int s = q * 256 + t;
        int r = s >> 7, c4 = s & 127;
        float4 v = *(const float4*)(Vn + (b * 128 + ch * 64 + r) * 512 + c4 * 4);
        *(float4*)(VcB + r * 2048 + ((c4 * 16) ^ ((r & 7) << 4))) = v;
      }
      __syncthreads();
      float acc0[4] = {0.f,0.f,0.f,0.f}, acc1[4] = {0.f,0.f,0.f,0.f};
      #pragma unroll 4
      for (int n = 0; n < 64; ++n) {
        float2 vv = *(const float2*)(VcB + n * 2048 + ((t * 8) ^ ((n & 7) << 4)));
        #pragma unroll
        for (int i = 0; i < 4; ++i) {
          float a = Asm[i][ch * 64 + n];
          acc0[i] = fmaf(a, vv.x, acc0[i]);
          acc1[i] = fmaf(a, vv.y, acc1[i]);
        }
      }
      #pragma unroll
      for (int i = 0; i < 4; ++i) {
        Qt[i][t * 2]     -= acc0[i];
        Qt[i][t * 2 + 1] -= acc1[i];
      }
    }
  }
  __syncthreads();
  // ---- epilogue: fragment-order bf16 Q
  {
    int i = t >> 6, ks = (t >> 2) & 15, lg = t & 3;
    int r = m0 + i;
    int nt = r >> 4, l = lg * 16 + (r & 15);
    const float* src = &Qt[i][ks * 32 + lg * 8];
    frag v;
    #pragma unroll
    for (int j = 0; j < 8; ++j) v[j] = (short)f2bf(src[j]);
    *(frag*)(Qf + ((size_t)(ks * 32 + nt) * 64 + l) * 8) = v;
  }
}

// ---------------------------------------------------------------------------
// out[m][n] = sum_k x[m][k] * Q[n][k]   M=131072 N=512 K=512
// BM=64, BN=512 (x read once), BK=64. 8 waves, wave w -> cols [w*64,w*64+64).
// A: f32->bf16 staged in 2x8KB swizzled LDS. B: direct global from Qf frags.
// ---------------------------------------------------------------------------
__global__ __launch_bounds__(512, 4) void final_gemm(const float* __restrict__ X,
                                                     const ushort_t* __restrict__ Qf,
                                                     float* __restrict__ out) {
  __shared__ __align__(16) ushort_t As[2][64 * 64];   // 2 x 8 KB
  const int tid = threadIdx.x;
  const int w = tid >> 6, lane = tid & 63;
  const int m0 = blockIdx.x * 64;
  const int row = tid >> 3, seg = tid & 7;            // staging coords

  f32x4 acc[4][4];
  #pragma unroll
  for (int i = 0; i < 4; ++i)
    #pragma unroll
    for (int j = 0; j < 4; ++j) acc[i][j] = (f32x4){0.f, 0.f, 0.f, 0.f};

  // prologue: stage kt=0
  {
    const float4* src = (const float4*)(X + (m0 + row) * 512 + seg * 8);
    float4 f0 = src[0], f1 = src[1];
    frag v;
    v[0]=(short)f2bf(f0.x); v[1]=(short)f2bf(f0.y); v[2]=(short)f2bf(f0.z); v[3]=(short)f2bf(f0.w);
    v[4]=(short)f2bf(f1.x); v[5]=(short)f2bf(f1.y); v[6]=(short)f2bf(f1.z); v[7]=(short)f2bf(f1.w);
    *(frag*)((char*)As[0] + row * 128 + ((seg * 16) ^ ((row & 7) << 4))) = v;
  }

  int cur = 0;
  for (int kt = 0; kt < 8; ++kt) {
    float4 f0, f1;
    if (kt < 7) {                       // T14: issue next x-loads early
      const float4* src = (const float4*)(X + (m0 + row) * 512 + (kt + 1) * 64 + seg * 8);
      f0 = src[0]; f1 = src[1];
    }
    __syncthreads();

    #pragma unroll
    for (int ks2 = 0; ks2 < 2; ++ks2) {
      const int ks = kt * 2 + ks2;
      frag bfr[4];
      #pragma unroll
      for (int j = 0; j < 4; ++j) {
        int nt = w * 4 + j;
        bfr[j] = *(const frag*)(Qf + ((size_t)(ks * 32 + nt) * 64 + lane) * 8);
      }
      frag a[4];
      const int kb = ks2 * 64 + ((lane >> 4) << 4);
      #pragma unroll
      for (int mf = 0; mf < 4; ++mf) {
        int r = mf * 16 + (lane & 15);
        a[mf] = *(const frag*)((const char*)As[cur] + r * 128 + (kb ^ ((r & 7) << 4)));
      }
      #pragma unroll
      for (int mf = 0; mf < 4; ++mf)
        #pragma unroll
        for (int j = 0; j < 4; ++j)
          acc[mf][j] = __builtin_amdgcn_mfma_f32_16x16x32_bf16(a[mf], bfr[j], acc[mf][j], 0, 0, 0);
    }

    if (kt < 7) {
      frag v;
      v[0]=(short)f2bf(f0.x); v[1]=(short)f2bf(f0.y); v[2]=(short)f2bf(f0.z); v[3]=(short)f2bf(f0.w);
      v[4]=(short)f2bf(f1.x); v[5]=(short)f2bf(f1.y); v[6]=(short)f2bf(f1.z); v[7]=(short)f2bf(f1.w);
      *(frag*)((char*)As[cur ^ 1] + row * 128 + ((seg * 16) ^ ((row & 7) << 4))) = v;
      cur ^= 1;
    }
  }

  // epilogue: C/D map col=lane&15, row=(lane>>4)*4+reg
  #pragma unroll
  for (int mf = 0; mf < 4; ++mf) {
    int rbase = m0 + mf * 16 + ((lane >> 4) << 2);
    #pragma unroll
    for (int j = 0; j < 4; ++j) {
      int col = w * 64 + j * 16 + (lane & 15);
      #pragma unroll
      for (int r = 0; r < 4; ++r)
        out[(size_t)(rbase + r) * 512 + col] = acc[mf][j][r];
    }
  }
}

extern "C" void kernel_launch(void* const* d_in, const int* in_sizes, int n_in,
                              void* d_out, int out_size, void* d_ws, size_t ws_size,
                              hipStream_t stream) {
  const float* x = (const float*)d_in[0];
  const float* V = (const float*)d_in[1];   // hd_vecs[0]: 512 x 512
  float* out = (float*)d_out;
  float* ws  = (float*)d_ws;

  float*    Vn = ws;                          // 262144 f32
  float*    GT = ws + 262144;                 // 65536 f32 (G -> Tt in place)
  ushort_t* Qf = (ushort_t*)(ws + 327680);    // 262144 bf16 (fragment order)

  normalize_kernel<<<128, 256, 0, stream>>>(V, Vn);
  gram_kernel<<<128, 256, 0, stream>>>(Vn, GT);
  trinv_kernel<<<4, 256, 0, stream>>>(GT);
  chain_kernel<<<128, 256, 0, stream>>>(Vn, GT, Qf);
  final_gemm<<<2048, 512, 0, stream>>>(x, Qf, out);
}

// Round 4
// 294.542 us; speedup vs baseline: 1.5911x; 1.1469x over previous
//
#include <hip/hip_runtime.h>
#include <hip/hip_bf16.h>
#include <stdint.h>

#define EPS 1e-6f

typedef unsigned short ushort_t;
using frag  = __attribute__((ext_vector_type(8))) short;   // 8 bf16
using f32x4 = __attribute__((ext_vector_type(4))) float;   // MFMA acc
using fv4   = __attribute__((ext_vector_type(4))) float;

#define SWAITLG() asm volatile("s_waitcnt lgkmcnt(0)" ::: "memory")

__device__ __forceinline__ ushort_t f2bf(float f) {
  uint32_t u = __builtin_bit_cast(uint32_t, f);
  u += 0x7FFFu + ((u >> 16) & 1u);          // round-to-nearest-even
  return (ushort_t)(u >> 16);
}

__device__ __forceinline__ frag pack8(float4 f0, float4 f1) {
  frag v;
  v[0]=(short)f2bf(f0.x); v[1]=(short)f2bf(f0.y); v[2]=(short)f2bf(f0.z); v[3]=(short)f2bf(f0.w);
  v[4]=(short)f2bf(f1.x); v[5]=(short)f2bf(f1.y); v[6]=(short)f2bf(f1.z); v[7]=(short)f2bf(f1.w);
  return v;
}

// ---------------------------------------------------------------------------
// P1: normalize rows. One wave per row (512 rows).
// ---------------------------------------------------------------------------
__global__ __launch_bounds__(256) void normalize_kernel(const float* __restrict__ V,
                                                        float* __restrict__ Vn) {
  const int gw   = blockIdx.x * 4 + (threadIdx.x >> 6);   // row 0..511
  const int lane = threadIdx.x & 63;
  const float4* src = (const float4*)(V + (size_t)gw * 512) + lane * 2;
  float4 a = src[0], c = src[1];
  float s = a.x*a.x + a.y*a.y + a.z*a.z + a.w*a.w
          + c.x*c.x + c.y*c.y + c.z*c.z + c.w*c.w;
  #pragma unroll
  for (int off = 32; off; off >>= 1) s += __shfl_xor(s, off);
  float inv = 1.f / (sqrtf(s) + EPS);
  float4 na = make_float4(a.x*inv, a.y*inv, a.z*inv, a.w*inv);
  float4 nc = make_float4(c.x*inv, c.y*inv, c.z*inv, c.w*inv);
  float4* dst = (float4*)(Vn + (size_t)gw * 512) + lane * 2;
  dst[0] = na; dst[1] = nc;
}

// ---------------------------------------------------------------------------
// P2: G[b][i][j] = <Vn_b[i], Vn_b[j]>, j>i. Block per (b,i); 4 waves split j.
// ---------------------------------------------------------------------------
__global__ __launch_bounds__(256) void gram_kernel(const float* __restrict__ Vn,
                                                   float* __restrict__ G) {
  const int gi = blockIdx.x;                  // b*128 + i
  const int b = gi >> 7, i = gi & 127;
  const int w = threadIdx.x >> 6, lane = threadIdx.x & 63;
  const float4* ri = (const float4*)(Vn + (size_t)gi * 512) + lane * 2;
  float4 a0 = ri[0], a1 = ri[1];
  for (int j = i + 1 + w; j < 128; j += 4) {
    const float4* rj = (const float4*)(Vn + (size_t)(b * 128 + j) * 512) + lane * 2;
    float4 c0 = rj[0], c1 = rj[1];
    float s = a0.x*c0.x + a0.y*c0.y + a0.z*c0.z + a0.w*c0.w
            + a1.x*c1.x + a1.y*c1.y + a1.z*c1.z + a1.w*c1.w;
    #pragma unroll
    for (int off = 32; off; off >>= 1) s += __shfl_xor(s, off);
    if (lane == 0) G[(size_t)gi * 128 + j] = s;
  }
}

// ---------------------------------------------------------------------------
// P3: Tt = transpose((0.5 I + triu(G,1))^-1) per 128-block, in place over G.
// ---------------------------------------------------------------------------
__global__ __launch_bounds__(256) void trinv_kernel(float* __restrict__ GT) {
  __shared__ float Gs[128][132];
  __shared__ float Ai[64][68];
  __shared__ float Di[64][68];
  __shared__ float C1[64][68];
  const int b = blockIdx.x, tid = threadIdx.x;
  float* Gg = GT + b * 16384;

  {
    const int r = tid >> 1, h = tid & 1;
    const float4* src = (const float4*)(Gg + r * 128 + h * 64);
    float4* dst = (float4*)(&Gs[r][h * 64]);
    #pragma unroll
    for (int e = 0; e < 16; ++e) dst[e] = src[e];
  }
  __syncthreads();

  const int wave = tid >> 6, lane = tid & 63;
  if (wave < 2) {
    const int o = wave * 64;
    float t[64];
    #pragma unroll
    for (int i = 63; i >= 0; --i) {
      float s = (i == lane) ? 1.f : 0.f;
      #pragma unroll
      for (int j = i + 1; j < 64; ++j) s -= Gs[o + i][o + j] * t[j];
      t[i] = 2.f * s;
    }
    float (*OUT)[68] = wave ? Di : Ai;
    #pragma unroll
    for (int i = 0; i < 64; ++i) OUT[i][lane] = t[i];
  }
  __syncthreads();

  const int i0 = (tid >> 4) << 2;
  const int j0 = (tid & 15) << 2;

  {  // C1 = B * Di
    fv4 acc[4] = {};
    for (int l = 0; l < 64; l += 4) {
      fv4 g[4], d[4];
      #pragma unroll
      for (int r = 0; r < 4; ++r) g[r] = *(const fv4*)(&Gs[i0 + r][64 + l]);
      #pragma unroll
      for (int r = 0; r < 4; ++r) d[r] = *(const fv4*)(&Di[l + r][j0]);
      #pragma unroll
      for (int r = 0; r < 4; ++r)
        #pragma unroll
        for (int l2 = 0; l2 < 4; ++l2)
          #pragma unroll
          for (int q = 0; q < 4; ++q)
            acc[r][q] = fmaf(g[r][l2], d[l2][q], acc[r][q]);
    }
    #pragma unroll
    for (int r = 0; r < 4; ++r) *(fv4*)(&C1[i0 + r][j0]) = acc[r];
  }
  __syncthreads();

  {  // corner = -Ai*C1, write transposed
    fv4 acc[4] = {};
    for (int l = 0; l < 64; l += 4) {
      fv4 g[4], d[4];
      #pragma unroll
      for (int r = 0; r < 4; ++r) g[r] = *(const fv4*)(&Ai[i0 + r][l]);
      #pragma unroll
      for (int r = 0; r < 4; ++r) d[r] = *(const fv4*)(&C1[l + r][j0]);
      #pragma unroll
      for (int r = 0; r < 4; ++r)
        #pragma unroll
        for (int l2 = 0; l2 < 4; ++l2)
          #pragma unroll
          for (int q = 0; q < 4; ++q)
            acc[r][q] = fmaf(g[r][l2], d[l2][q], acc[r][q]);
    }
    #pragma unroll
    for (int r = 0; r < 4; ++r)
      #pragma unroll
      for (int q = 0; q < 4; ++q)
        Gg[(64 + j0 + q) * 128 + (i0 + r)] = -acc[r][q];
  }

  {
    const int j = tid >> 1, h = tid & 1;
    if (j < 64) {
      if (h == 0) { for (int i = 0; i < 64; ++i) Gg[j * 128 + i] = Ai[i][j]; }
      else        { for (int i = 0; i < 64; ++i) Gg[j * 128 + 64 + i] = 0.f; }
    } else if (h == 1) {
      for (int i = 0; i < 64; ++i) Gg[j * 128 + 64 + i] = Di[i][j - 64];
    }
  }
}

// ---------------------------------------------------------------------------
// Fused chain (de-staged: Vn read direct from L1/L2, no LDS tile staging).
// Block owns 4 Q-rows; per b: P = Qt·Vn_b^T ; A = P·Tt^T ; Qt -= A·Vn_b.
// Epilogue writes Qf in MFMA-B fragment order (bf16).
// ---------------------------------------------------------------------------
__global__ __launch_bounds__(256) void chain_kernel(const float* __restrict__ Vn,
                                                    const float* __restrict__ Tt,
                                                    ushort_t* __restrict__ Qf) {
  __shared__ float Qt[4][512];          // 8 KB
  __shared__ float Pp[4][4][64];        // 4 KB wave partials
  __shared__ float Ps[4][128];          // 2 KB
  __shared__ float Asm[4][128];         // 2 KB
  const int t = threadIdx.x, w = t >> 6, lane = t & 63;
  const int m0 = blockIdx.x * 4;

  for (int idx = t; idx < 2048; idx += 256) {
    int i = idx >> 9, k = idx & 511;
    Qt[i][k] = (m0 + i == k) ? 1.f : 0.f;
  }

  for (int b = 0; b < 4; ++b) {
    // ---- P[4][128]
    if (b == 0) {
      __syncthreads();
      if (t < 128) {
        #pragma unroll
        for (int i = 0; i < 4; ++i) Ps[i][t] = Vn[t * 512 + m0 + i];
      }
      __syncthreads();
    } else {
      for (int ch = 0; ch < 2; ++ch) {
        __syncthreads();                       // Pp reuse + Qt stability
        const int n = ch * 64 + lane;
        const float* vrow = Vn + (size_t)(b * 128 + n) * 512;
        float pa[4] = {0.f, 0.f, 0.f, 0.f};
        #pragma unroll 8
        for (int k4 = 0; k4 < 32; ++k4) {
          int kk = w * 128 + k4 * 4;
          float4 vv = *(const float4*)(vrow + kk);
          #pragma unroll
          for (int i = 0; i < 4; ++i) {
            float4 qq = *(const float4*)(&Qt[i][kk]);
            pa[i] += qq.x*vv.x + qq.y*vv.y + qq.z*vv.z + qq.w*vv.w;
          }
        }
        #pragma unroll
        for (int i = 0; i < 4; ++i) Pp[w][i][lane] = pa[i];
        __syncthreads();
        if (w < 2) {
          #pragma unroll
          for (int i2 = 0; i2 < 2; ++i2) {
            int i = w * 2 + i2;
            Ps[i][ch * 64 + lane] = Pp[0][i][lane] + Pp[1][i][lane]
                                  + Pp[2][i][lane] + Pp[3][i][lane];
          }
        }
      }
      __syncthreads();
    }
    // ---- A[i][n] = sum_j P[i][j] * Tt_b[n][j]; thread: n=t>>1, j-half=t&1
    {
      const float* trow = Tt + b * 16384 + (t >> 1) * 128 + (t & 1) * 64;
      float aa[4] = {0.f, 0.f, 0.f, 0.f};
      #pragma unroll 4
      for (int j4 = 0; j4 < 16; ++j4) {
        float4 tv = *(const float4*)(trow + j4 * 4);
        int j = (t & 1) * 64 + j4 * 4;
        #pragma unroll
        for (int i = 0; i < 4; ++i) {
          float4 pv = *(const float4*)(&Ps[i][j]);
          aa[i] += pv.x*tv.x + pv.y*tv.y + pv.z*tv.z + pv.w*tv.w;
        }
      }
      #pragma unroll
      for (int i = 0; i < 4; ++i) {
        float o = __shfl_xor(aa[i], 1);
        if ((t & 1) == 0) Asm[i][t >> 1] = aa[i] + o;
      }
    }
    __syncthreads();                           // Asm visible
    // ---- update: Qt[i][2t],[2t+1] -= sum_n A[i][n] Vn_b[n][...]
    {
      float acc0[4] = {0.f,0.f,0.f,0.f}, acc1[4] = {0.f,0.f,0.f,0.f};
      const float* vb = Vn + (size_t)b * 65536 + t * 2;
      #pragma unroll 4
      for (int n = 0; n < 128; ++n) {
        float2 vv = *(const float2*)(vb + (size_t)n * 512);
        #pragma unroll
        for (int i = 0; i < 4; ++i) {
          float a = Asm[i][n];
          acc0[i] = fmaf(a, vv.x, acc0[i]);
          acc1[i] = fmaf(a, vv.y, acc1[i]);
        }
      }
      #pragma unroll
      for (int i = 0; i < 4; ++i) {
        Qt[i][t * 2]     -= acc0[i];
        Qt[i][t * 2 + 1] -= acc1[i];
      }
    }
  }
  __syncthreads();
  // ---- epilogue: fragment-order bf16 Q
  {
    int i = t >> 6, ks = (t >> 2) & 15, lg = t & 3;
    int r = m0 + i;
    int nt = r >> 4, l = lg * 16 + (r & 15);
    const float* src = &Qt[i][ks * 32 + lg * 8];
    frag v;
    #pragma unroll
    for (int j = 0; j < 8; ++j) v[j] = (short)f2bf(src[j]);
    *(frag*)(Qf + ((size_t)(ks * 32 + nt) * 64 + l) * 8) = v;
  }
}

// ---------------------------------------------------------------------------
// out[m][n] = sum_k x[m][k] * Q[n][k]   M=131072 N=512 K=512
// BM=64, BN=512 (x read once), BK=64. 8 waves, wave w -> cols [w*64,w*64+64).
// One raw s_barrier per kt (lgkm fence only — vmcnt NEVER drained at barrier).
// x prefetch 2-deep (fE/fO ping-pong). LDS-staged coalesced epilogue.
// ---------------------------------------------------------------------------
__global__ __launch_bounds__(512, 3) void final_gemm(const float* __restrict__ X,
                                                     const ushort_t* __restrict__ Qf,
                                                     float* __restrict__ out) {
  __shared__ __align__(16) ushort_t As[2][64 * 64];   // 2 x 8 KB, swizzled
  __shared__ __align__(16) float Ep[16][516];         // 33 KB epilogue staging
  const int tid = threadIdx.x;
  const int w = tid >> 6, lane = tid & 63;
  const int m0 = blockIdx.x * 64;
  const int row = tid >> 3, seg = tid & 7;
  const int sw_off = row * 128 + ((seg * 16) ^ ((row & 7) << 4));
  const float4* xs = (const float4*)(X + (size_t)(m0 + row) * 512) + seg * 2;

  f32x4 acc[4][4];
  #pragma unroll
  for (int i = 0; i < 4; ++i)
    #pragma unroll
    for (int j = 0; j < 4; ++j) acc[i][j] = (f32x4){0.f, 0.f, 0.f, 0.f};

  // prologue: tile0 -> As[0]; issue tile1 into fO
  float4 fE0 = xs[0], fE1 = xs[1];
  float4 fO0 = xs[16], fO1 = xs[17];
  *(frag*)((char*)As[0] + sw_off) = pack8(fE0, fE1);
  SWAITLG();
  __builtin_amdgcn_s_barrier();

  #pragma unroll
  for (int kt = 0; kt < 8; ++kt) {
    const int cur = kt & 1;
    // B-fragment loads for this kt (L2-resident Qf)
    frag b0[4], b1[4];
    #pragma unroll
    for (int j = 0; j < 4; ++j) {
      int nt = w * 4 + j;
      b0[j] = *(const frag*)(Qf + ((size_t)((2*kt)     * 32 + nt) * 64 + lane) * 8);
      b1[j] = *(const frag*)(Qf + ((size_t)((2*kt + 1) * 32 + nt) * 64 + lane) * 8);
    }
    // issue x-loads for tile kt+2 (2-deep prefetch)
    if (kt < 6) {
      if (cur == 0) { fE0 = xs[(kt + 2) * 16]; fE1 = xs[(kt + 2) * 16 + 1]; }
      else          { fO0 = xs[(kt + 2) * 16]; fO1 = xs[(kt + 2) * 16 + 1]; }
    }
    // compute from As[cur]
    frag a[4];
    {   // ks2 = 0
      const int kb = (lane >> 4) << 4;
      #pragma unroll
      for (int mf = 0; mf < 4; ++mf) {
        int r = mf * 16 + (lane & 15);
        a[mf] = *(const frag*)((const char*)As[cur] + r * 128 + (kb ^ ((r & 7) << 4)));
      }
      #pragma unroll
      for (int mf = 0; mf < 4; ++mf)
        #pragma unroll
        for (int j = 0; j < 4; ++j)
          acc[mf][j] = __builtin_amdgcn_mfma_f32_16x16x32_bf16(a[mf], b0[j], acc[mf][j], 0, 0, 0);
    }
    {   // ks2 = 1
      const int kb = 64 + ((lane >> 4) << 4);
      #pragma unroll
      for (int mf = 0; mf < 4; ++mf) {
        int r = mf * 16 + (lane & 15);
        a[mf] = *(const frag*)((const char*)As[cur] + r * 128 + (kb ^ ((r & 7) << 4)));
      }
      #pragma unroll
      for (int mf = 0; mf < 4; ++mf)
        #pragma unroll
        for (int j = 0; j < 4; ++j)
          acc[mf][j] = __builtin_amdgcn_mfma_f32_16x16x32_bf16(a[mf], b1[j], acc[mf][j], 0, 0, 0);
    }
    // write tile kt+1 into As[cur^1]
    if (kt < 7) {
      float4 c0 = (cur == 0) ? fO0 : fE0;
      float4 c1 = (cur == 0) ? fO1 : fE1;
      *(frag*)((char*)As[cur ^ 1] + sw_off) = pack8(c0, c1);
    }
    SWAITLG();
    __builtin_amdgcn_s_barrier();
  }

  // LDS-staged epilogue: 4 chunks of 16 rows, fully-coalesced float4 stores
  #pragma unroll
  for (int mf = 0; mf < 4; ++mf) {
    if (mf > 0) __builtin_amdgcn_s_barrier();       // Ep readers done
    #pragma unroll
    for (int j = 0; j < 4; ++j) {
      int col = w * 64 + j * 16 + (lane & 15);
      #pragma unroll
      for (int r = 0; r < 4; ++r)
        Ep[((lane >> 4) << 2) + r][col] = acc[mf][j][r];
    }
    SWAITLG();
    __builtin_amdgcn_s_barrier();
    #pragma unroll
    for (int e = 0; e < 4; ++e) {
      int idx = e * 512 + tid;
      int rr = idx >> 7, c4 = idx & 127;
      float4 v = *(const float4*)(&Ep[rr][c4 * 4]);
      *(float4*)(out + (size_t)(m0 + mf * 16 + rr) * 512 + c4 * 4) = v;
    }
  }
}

extern "C" void kernel_launch(void* const* d_in, const int* in_sizes, int n_in,
                              void* d_out, int out_size, void* d_ws, size_t ws_size,
                              hipStream_t stream) {
  const float* x = (const float*)d_in[0];
  const float* V = (const float*)d_in[1];   // hd_vecs[0]: 512 x 512
  float* out = (float*)d_out;
  float* ws  = (float*)d_ws;

  float*    Vn = ws;                          // 262144 f32
  float*    GT = ws + 262144;                 // 65536 f32 (G -> Tt in place)
  ushort_t* Qf = (ushort_t*)(ws + 327680);    // 262144 bf16 (fragment order)

  normalize_kernel<<<128, 256, 0, stream>>>(V, Vn);
  gram_kernel<<<512, 256, 0, stream>>>(Vn, GT);
  trinv_kernel<<<4, 256, 0, stream>>>(GT);
  chain_kernel<<<128, 256, 0, stream>>>(Vn, GT, Qf);
  final_gemm<<<2048, 512, 0, stream>>>(x, Qf, out);
}